// Round 1
// baseline (1162.046 us; speedup 1.0000x reference)
//
#include <hip/hip_runtime.h>

#define SEQ 256
#define HID 400
#define NWG 25          // workgroups per LSTM direction
#define HSL 16          // h outputs per workgroup (25*16 = 400)

#define N_ARC 65536
#define N_SIB 200000
#define N_GP  200000
#define N_GSIB 300000

__device__ __forceinline__ float fsig(float x) {
  // 1/(1+e^-x); saturates correctly at +/-inf
  return __builtin_amdgcn_rcpf(1.f + __expf(-x));
}
__device__ __forceinline__ float ftanh(float x) {
  // 1 - 2/(1+e^{2x}); exact at saturation (inf -> 1, 0 -> -1)
  return 1.f - 2.f * __builtin_amdgcn_rcpf(1.f + __expf(2.f * x));
}

// ---------------------------------------------------------------------------
// Kernel 1: z_in[d][s][r] = b[r] + sum_k x_scan[d][s][k] * Wih[r][k]
// x_scan[0][s] = x[s], x_scan[1][s] = x[255-s];  x = [word_emb|tag_emb]
// grid: 64 blocks = 2 dirs x 32 s-tiles of 8
// ---------------------------------------------------------------------------
__global__ __launch_bounds__(256) void k_zin(
    const int* __restrict__ words, const int* __restrict__ tags,
    const float* __restrict__ word_emb, const float* __restrict__ tag_emb,
    const float* __restrict__ Wih_f, const float* __restrict__ b_f,
    const float* __restrict__ Wih_b, const float* __restrict__ b_b,
    float* __restrict__ z_in) {
  int d = blockIdx.x >> 5;
  int st = blockIdx.x & 31;
  const float* Wih = d ? Wih_b : Wih_f;
  const float* b = d ? b_b : b_f;
  __shared__ float xs[8][120];
  int tid = threadIdx.x;
  for (int idx = tid; idx < 8 * 120; idx += 256) {
    int r = idx / 120, k = idx - r * 120;
    int s = st * 8 + r;
    int t = d ? (SEQ - 1 - s) : s;
    float v = (k < 100) ? word_emb[words[t] * 100 + k]
                        : tag_emb[tags[t] * 20 + (k - 100)];
    xs[r][k] = v;
  }
  __syncthreads();
  for (int row = tid; row < 1600; row += 256) {
    const float4* w4 = reinterpret_cast<const float4*>(Wih + row * 120);
    float bb = b[row];
    float acc[8];
#pragma unroll
    for (int r = 0; r < 8; ++r) acc[r] = bb;
    for (int k4 = 0; k4 < 30; ++k4) {
      float4 w = w4[k4];
#pragma unroll
      for (int r = 0; r < 8; ++r) {
        const float* x = &xs[r][k4 * 4];
        acc[r] += w.x * x[0] + w.y * x[1] + w.z * x[2] + w.w * x[3];
      }
    }
    for (int r = 0; r < 8; ++r) {
      int s = st * 8 + r;
      z_in[(d * SEQ + s) * 1600 + row] = acc[r];
    }
  }
}

// ---------------------------------------------------------------------------
// Kernel 2: BiLSTM recurrence. 50 WGs (25/dir) x 256 threads, weights in VGPRs.
// thread t: lr = t>>2 in [0,64) -> row = gate*400 + slot*16 + (lr&15),
//           q = t&3 -> k-chunk [q*100, q*100+100)
// Per step: partial dots -> 4-lane shfl reduce -> gates (t<16) -> publish h
// slice to h_glob double buffer -> flag -> poll all flags -> reload h.
// ---------------------------------------------------------------------------
__global__ __launch_bounds__(256) void k_lstm(
    const float* __restrict__ Whh_f, const float* __restrict__ Whh_b,
    const float* __restrict__ z_in,  // [2][256][1600]
    float* __restrict__ states,      // [256][800]
    float* h_glob,                   // [2][2][400]
    int* flags) {                    // [2][25]
  int w = blockIdx.x;
  int dir = w / NWG;
  int slot = w - dir * NWG;
  int t = threadIdx.x;
  int lr = t >> 2, q = t & 3;
  int gate = lr >> 4, jj = lr & 15;
  int row = gate * 400 + slot * HSL + jj;
  const float* Whh = dir ? Whh_b : Whh_f;

  // resident weights: 25 float4 = 100 VGPRs
  float4 wreg[25];
  const float4* wsrc =
      reinterpret_cast<const float4*>(Whh + row * 400 + q * 100);
#pragma unroll
  for (int i = 0; i < 25; ++i) wreg[i] = wsrc[i];

  __shared__ float4 h4[100];  // h[400]
  __shared__ float sums[64];
  float* h_lds = reinterpret_cast<float*>(h4);
  if (t < 100) h4[t] = make_float4(0.f, 0.f, 0.f, 0.f);
  float c = 0.f;  // cell state, valid for t<16
  __syncthreads();

  int* myflags = flags + dir * NWG;
  float* hg = h_glob + dir * 800;  // two buffers of 400
  const float* zbase = z_in + (size_t)dir * SEQ * 1600;

  for (int s = 0; s < SEQ; ++s) {
    float zv = 0.f;
    if (q == 0) zv = zbase[s * 1600 + row];
    float acc = 0.f;
    const float4* hp = h4 + q * 25;
#pragma unroll
    for (int i = 0; i < 25; ++i) {
      float4 h = hp[i];
      float4 ww = wreg[i];
      acc += ww.x * h.x + ww.y * h.y + ww.z * h.z + ww.w * h.w;
    }
    acc += __shfl_xor(acc, 1);
    acc += __shfl_xor(acc, 2);
    if (q == 0) sums[lr] = acc + zv;
    __syncthreads();
    if (t < HSL) {
      float zi = sums[t], zf = sums[16 + t], zg = sums[32 + t],
            zo = sums[48 + t];
      float ig = fsig(zi), fg = fsig(zf), gg = ftanh(zg), og = fsig(zo);
      c = fg * c + ig * gg;
      float hnew = og * ftanh(c);
      int buf = (s + 1) & 1;
      __hip_atomic_store(&hg[buf * 400 + slot * HSL + t], hnew,
                         __ATOMIC_RELAXED, __HIP_MEMORY_SCOPE_AGENT);
      int torig = dir ? (SEQ - 1 - s) : s;
      states[torig * 800 + dir * 400 + slot * HSL + t] = hnew;
    }
    __syncthreads();  // drains vmcnt: h stores complete before flag
    if (t == 0)
      __hip_atomic_store(&myflags[slot], s + 1, __ATOMIC_RELEASE,
                         __HIP_MEMORY_SCOPE_AGENT);
    if (s == SEQ - 1) break;
    if (t < NWG) {
      while (__hip_atomic_load(&myflags[t], __ATOMIC_ACQUIRE,
                               __HIP_MEMORY_SCOPE_AGENT) < s + 1) {
      }
    }
    __syncthreads();
    int buf = (s + 1) & 1;
    for (int idx = t; idx < 400; idx += 256) {
      h_lds[idx] = __hip_atomic_load(&hg[buf * 400 + idx], __ATOMIC_RELAXED,
                                     __HIP_MEMORY_SCOPE_AGENT);
    }
    __syncthreads();
  }
}

// ---------------------------------------------------------------------------
// Kernel 3: proj[p][s][m] = sum_k W_proj[p][m][k] * states[s][k]
// grid: 12 p x 16 s-tiles of 16. states tile in LDS, one m per thread.
// ---------------------------------------------------------------------------
__global__ __launch_bounds__(256) void k_proj(
    const float* __restrict__ W_proj,  // [12][200][800]
    const float* __restrict__ states,  // [256][800]
    float* __restrict__ proj) {        // [12][256][200]
  int p = blockIdx.x >> 4;
  int st = blockIdx.x & 15;
  __shared__ float s_lds[16][800];
  int tid = threadIdx.x;
  for (int idx = tid; idx < 16 * 800; idx += 256) {
    int si = idx / 800, k = idx - si * 800;
    s_lds[si][k] = states[(st * 16 + si) * 800 + k];
  }
  __syncthreads();
  if (tid < 200) {
    int m = tid;
    const float4* w4 =
        reinterpret_cast<const float4*>(W_proj + (p * 200 + m) * 800);
    float acc[16];
#pragma unroll
    for (int si = 0; si < 16; ++si) acc[si] = 0.f;
    for (int k4 = 0; k4 < 200; ++k4) {
      float4 w = w4[k4];
#pragma unroll
      for (int si = 0; si < 16; ++si) {
        float4 sv = *reinterpret_cast<const float4*>(&s_lds[si][k4 * 4]);
        acc[si] += w.x * sv.x + w.y * sv.y + w.z * sv.z + w.w * sv.w;
      }
    }
    for (int si = 0; si < 16; ++si)
      proj[(p * SEQ + st * 16 + si) * 200 + m] = acc[si];
  }
}

// ---------------------------------------------------------------------------
// Kernel 4: scoring. One output per thread; NT gathered rows of 200,
// tanh, dot with W_score row. Slot 2 gets the null-row substitution
// (index == SEQ) — harmless no-op for gp where indices < SEQ.
// ---------------------------------------------------------------------------
template <int NT>
__global__ __launch_bounds__(256) void k_score(
    const float* __restrict__ b0, const int* __restrict__ i0,
    const float* __restrict__ b1, const int* __restrict__ i1,
    const float* __restrict__ b2, const int* __restrict__ i2,
    const float* __restrict__ b3, const int* __restrict__ i3,
    const float* __restrict__ nullrow, const float* __restrict__ wrow,
    float* __restrict__ out, int N) {
  int n = blockIdx.x * 256 + threadIdx.x;
  if (n >= N) return;
  const float4* a0 = reinterpret_cast<const float4*>(b0 + i0[n] * 200);
  const float4* a1 = reinterpret_cast<const float4*>(b1 + i1[n] * 200);
  const float4* a2 = nullptr;
  const float4* a3 = nullptr;
  if constexpr (NT >= 3) {
    int ix = i2[n];
    const float* r2 = (ix >= SEQ) ? nullrow : b2 + ix * 200;
    a2 = reinterpret_cast<const float4*>(r2);
  }
  if constexpr (NT >= 4) {
    a3 = reinterpret_cast<const float4*>(b3 + i3[n] * 200);
  }
  const float4* aw = reinterpret_cast<const float4*>(wrow);
  float acc = 0.f;
#pragma unroll 2
  for (int i = 0; i < 50; ++i) {
    float4 s0 = a0[i];
    float4 s1 = a1[i];
    float x0 = s0.x + s1.x, x1 = s0.y + s1.y, x2 = s0.z + s1.z,
          x3 = s0.w + s1.w;
    if constexpr (NT >= 3) {
      float4 s2 = a2[i];
      x0 += s2.x; x1 += s2.y; x2 += s2.z; x3 += s2.w;
    }
    if constexpr (NT >= 4) {
      float4 s3 = a3[i];
      x0 += s3.x; x1 += s3.y; x2 += s3.z; x3 += s3.w;
    }
    float4 w = aw[i];
    acc += ftanh(x0) * w.x + ftanh(x1) * w.y + ftanh(x2) * w.z +
           ftanh(x3) * w.w;
  }
  out[n] = acc;
}

// ---------------------------------------------------------------------------
extern "C" void kernel_launch(void* const* d_in, const int* in_sizes, int n_in,
                              void* d_out, int out_size, void* d_ws,
                              size_t ws_size, hipStream_t stream) {
  const int* words = (const int*)d_in[0];
  const int* tags = (const int*)d_in[1];
  const int* arc_head = (const int*)d_in[2];
  const int* arc_mod = (const int*)d_in[3];
  const int* sib_head = (const int*)d_in[4];
  const int* sib_mod = (const int*)d_in[5];
  const int* sib_sib = (const int*)d_in[6];
  const int* gp_head = (const int*)d_in[7];
  const int* gp_mod = (const int*)d_in[8];
  const int* gp_grand = (const int*)d_in[9];
  const int* gsib_head = (const int*)d_in[10];
  const int* gsib_mod = (const int*)d_in[11];
  const int* gsib_sib = (const int*)d_in[12];
  const int* gsib_grand = (const int*)d_in[13];
  const float* word_emb = (const float*)d_in[14];
  const float* tag_emb = (const float*)d_in[15];
  const float* Wih_f = (const float*)d_in[16];
  const float* Whh_f = (const float*)d_in[17];
  const float* b_f = (const float*)d_in[18];
  const float* Wih_b = (const float*)d_in[19];
  const float* Whh_b = (const float*)d_in[20];
  const float* b_b = (const float*)d_in[21];
  const float* W_proj = (const float*)d_in[22];
  const float* W_score = (const float*)d_in[23];
  const float* null_sib = (const float*)d_in[24];
  float* out = (float*)d_out;

  float* ws = (float*)d_ws;
  float* z_in = ws;                    // 2*256*1600 = 819200
  float* states = ws + 819200;         // 256*800   = 204800
  float* proj = ws + 1024000;          // 12*256*200 = 614400
  float* h_glob = ws + 1638400;        // 2*2*400   = 1600
  int* flags = (int*)(ws + 1640000);   // 64 ints

  // flags must be zero each launch (monotonic step tags within one launch;
  // stale values from a previous replay would break the spin barrier).
  hipMemsetAsync(flags, 0, 64 * sizeof(int), stream);

  k_zin<<<64, 256, 0, stream>>>(words, tags, word_emb, tag_emb, Wih_f, b_f,
                                Wih_b, b_b, z_in);
  k_lstm<<<2 * NWG, 256, 0, stream>>>(Whh_f, Whh_b, z_in, states, h_glob,
                                      flags);
  k_proj<<<12 * 16, 256, 0, stream>>>(W_proj, states, proj);

  const float* P = proj;
  const size_t TB = (size_t)SEQ * 200;  // per-table stride
  // arc: tanh(a_h[head] + a_m[mod]) . W_score[0]
  k_score<2><<<(N_ARC + 255) / 256, 256, 0, stream>>>(
      P + 0 * TB, arc_head, P + 1 * TB, arc_mod, nullptr, nullptr, nullptr,
      nullptr, null_sib, W_score + 0, out, N_ARC);
  // sib: tanh(s_h[h] + s_m[m] + sib_tab[s]) . W_score[1]
  k_score<3><<<(N_SIB + 255) / 256, 256, 0, stream>>>(
      P + 5 * TB, sib_head, P + 6 * TB, sib_mod, P + 7 * TB, sib_sib, nullptr,
      nullptr, null_sib, W_score + 200, out + N_ARC, N_SIB);
  // gp: tanh(g_h[h] + g_m[m] + g_g[g]) . W_score[2]
  k_score<3><<<(N_GP + 255) / 256, 256, 0, stream>>>(
      P + 3 * TB, gp_head, P + 4 * TB, gp_mod, P + 2 * TB, gp_grand, nullptr,
      nullptr, null_sib, W_score + 400, out + N_ARC + N_SIB, N_GP);
  // gsib: tanh(gs_h[h] + gs_m[m] + gsib_tab[s] + gs_g[g]) . W_score[3]
  k_score<4><<<(N_GSIB + 255) / 256, 256, 0, stream>>>(
      P + 8 * TB, gsib_head, P + 9 * TB, gsib_mod, P + 10 * TB, gsib_sib,
      P + 11 * TB, gsib_grand, null_sib, W_score + 600,
      out + N_ARC + N_SIB + N_GP, N_GSIB);
}

// Round 2
// 772.835 us; speedup vs baseline: 1.5036x; 1.5036x over previous
//
#include <hip/hip_runtime.h>

#define SEQ 256
#define HID 400
#define NWG 25          // workgroups per LSTM direction
#define HSL 16          // h outputs per workgroup (25*16 = 400)

#define N_ARC 65536
#define N_SIB 200000
#define N_GP  200000
#define N_GSIB 300000

#define SENT 0x7F7F7F7Fu   // memset(0x7F) pattern = 3.39e38f; |h|<=1 never hits it

__device__ __forceinline__ float fsig(float x) {
  return __builtin_amdgcn_rcpf(1.f + __expf(-x));
}
__device__ __forceinline__ float ftanh(float x) {
  return 1.f - 2.f * __builtin_amdgcn_rcpf(1.f + __expf(2.f * x));
}

// ---------------------------------------------------------------------------
// Kernel 1: z_in[d][s][r] = b[r] + sum_k x_scan[d][s][k] * Wih[r][k]
// ---------------------------------------------------------------------------
__global__ __launch_bounds__(256) void k_zin(
    const int* __restrict__ words, const int* __restrict__ tags,
    const float* __restrict__ word_emb, const float* __restrict__ tag_emb,
    const float* __restrict__ Wih_f, const float* __restrict__ b_f,
    const float* __restrict__ Wih_b, const float* __restrict__ b_b,
    float* __restrict__ z_in) {
  int d = blockIdx.x >> 5;
  int st = blockIdx.x & 31;
  const float* Wih = d ? Wih_b : Wih_f;
  const float* b = d ? b_b : b_f;
  __shared__ float xs[8][120];
  int tid = threadIdx.x;
  for (int idx = tid; idx < 8 * 120; idx += 256) {
    int r = idx / 120, k = idx - r * 120;
    int s = st * 8 + r;
    int t = d ? (SEQ - 1 - s) : s;
    float v = (k < 100) ? word_emb[words[t] * 100 + k]
                        : tag_emb[tags[t] * 20 + (k - 100)];
    xs[r][k] = v;
  }
  __syncthreads();
  for (int row = tid; row < 1600; row += 256) {
    const float4* w4 = reinterpret_cast<const float4*>(Wih + row * 120);
    float bb = b[row];
    float acc[8];
#pragma unroll
    for (int r = 0; r < 8; ++r) acc[r] = bb;
    for (int k4 = 0; k4 < 30; ++k4) {
      float4 w = w4[k4];
#pragma unroll
      for (int r = 0; r < 8; ++r) {
        const float* x = &xs[r][k4 * 4];
        acc[r] += w.x * x[0] + w.y * x[1] + w.z * x[2] + w.w * x[3];
      }
    }
    for (int r = 0; r < 8; ++r) {
      int s = st * 8 + r;
      z_in[(d * SEQ + s) * 1600 + row] = acc[r];
    }
  }
}

// ---------------------------------------------------------------------------
// Kernel 2: BiLSTM recurrence, sentinel-poll broadcast.
// 50 WGs x 256 threads. Weights VGPR-resident (launch_bounds(256,1)).
// Each step s writes its 16 h-values to a FRESH slot h_hist[dir][s][.] with
// relaxed agent atomics; consumers poll value != SENT per word (no flags, no
// fences needed: each word written exactly once, independently validated).
// ---------------------------------------------------------------------------
__global__ __launch_bounds__(256, 1) void k_lstm(
    const float* __restrict__ Whh_f, const float* __restrict__ Whh_b,
    const float* __restrict__ z_in,  // [2][256][1600]
    float* __restrict__ states,      // [256][800]
    float* h_hist) {                 // [2][256][400], poisoned 0x7F
  int w = blockIdx.x;
  int dir = w / NWG;
  int slot = w - dir * NWG;
  int t = threadIdx.x;
  int lr = t >> 2, q = t & 3;
  int gate = lr >> 4, jj = lr & 15;
  int row = gate * 400 + slot * HSL + jj;
  const float* Whh = dir ? Whh_b : Whh_f;

  float4 wreg[25];  // 100 VGPRs resident
  const float4* wsrc =
      reinterpret_cast<const float4*>(Whh + row * 400 + q * 100);
#pragma unroll
  for (int i = 0; i < 25; ++i) wreg[i] = wsrc[i];

  __shared__ float4 h4[100];  // h[400]
  __shared__ float sums[64];
  float* h_lds = reinterpret_cast<float*>(h4);
  if (t < 100) h4[t] = make_float4(0.f, 0.f, 0.f, 0.f);
  float c = 0.f;  // valid for t<16
  const float* zbase = z_in + (size_t)dir * SEQ * 1600;
  float* hh = h_hist + (size_t)dir * SEQ * 400;
  float zv = (q == 0) ? zbase[row] : 0.f;
  __syncthreads();

  for (int s = 0;; ++s) {
    // prefetch next step's z early so it overlaps poll+compute
    float znext = 0.f;
    if (q == 0 && s + 1 < SEQ) znext = zbase[(s + 1) * 1600 + row];
    float acc = 0.f;
    const float4* hp = h4 + q * 25;
#pragma unroll
    for (int i = 0; i < 25; ++i) {
      float4 h = hp[i];
      float4 ww = wreg[i];
      acc += ww.x * h.x + ww.y * h.y + ww.z * h.z + ww.w * h.w;
    }
    acc += __shfl_xor(acc, 1);
    acc += __shfl_xor(acc, 2);
    if (q == 0) sums[lr] = acc + zv;
    __syncthreads();  // also orders h4 reads (above) vs poll writes (below)
    if (t < HSL) {
      float zi = sums[t], zf = sums[16 + t], zg = sums[32 + t],
            zo = sums[48 + t];
      float ig = fsig(zi), fg = fsig(zf), gg = ftanh(zg), og = fsig(zo);
      c = fg * c + ig * gg;
      float hnew = og * ftanh(c);
      __hip_atomic_store(&hh[s * 400 + slot * HSL + t], hnew, __ATOMIC_RELAXED,
                         __HIP_MEMORY_SCOPE_AGENT);
      int torig = dir ? (SEQ - 1 - s) : s;
      states[torig * 800 + dir * 400 + slot * HSL + t] = hnew;
    }
    if (s == SEQ - 1) break;
    // poll this step's full h vector into LDS (overlaps producer gate work)
    const float* hs = hh + s * 400;
    for (int wd = t; wd < 400; wd += 256) {
      unsigned int u;
      do {
        u = __hip_atomic_load((const unsigned int*)&hs[wd], __ATOMIC_RELAXED,
                              __HIP_MEMORY_SCOPE_AGENT);
      } while (u == SENT);
      reinterpret_cast<unsigned int*>(h_lds)[wd] = u;
    }
    __syncthreads();
    zv = znext;
  }
}

// ---------------------------------------------------------------------------
// Kernel 3: proj[p][s][m] = sum_k W_proj[p][m][k] * states[s][k]
// ---------------------------------------------------------------------------
__global__ __launch_bounds__(256) void k_proj(
    const float* __restrict__ W_proj,  // [12][200][800]
    const float* __restrict__ states,  // [256][800]
    float* __restrict__ proj) {        // [12][256][200]
  int p = blockIdx.x >> 4;
  int st = blockIdx.x & 15;
  __shared__ float s_lds[16][800];
  int tid = threadIdx.x;
  for (int idx = tid; idx < 16 * 800; idx += 256) {
    int si = idx / 800, k = idx - si * 800;
    s_lds[si][k] = states[(st * 16 + si) * 800 + k];
  }
  __syncthreads();
  if (tid < 200) {
    int m = tid;
    const float4* w4 =
        reinterpret_cast<const float4*>(W_proj + (p * 200 + m) * 800);
    float acc[16];
#pragma unroll
    for (int si = 0; si < 16; ++si) acc[si] = 0.f;
    for (int k4 = 0; k4 < 200; ++k4) {
      float4 w = w4[k4];
#pragma unroll
      for (int si = 0; si < 16; ++si) {
        float4 sv = *reinterpret_cast<const float4*>(&s_lds[si][k4 * 4]);
        acc[si] += w.x * sv.x + w.y * sv.y + w.z * sv.z + w.w * sv.w;
      }
    }
    for (int si = 0; si < 16; ++si)
      proj[(p * SEQ + st * 16 + si) * 200 + m] = acc[si];
  }
}

// ---------------------------------------------------------------------------
// Kernel 4: scoring, 4 lanes per output. Consecutive lanes read consecutive
// float4s of each gathered row -> 64B coalesced requests (4x fewer than
// row-per-thread). shfl_xor reduce, lane 0 of each quad writes.
// ---------------------------------------------------------------------------
template <int NT>
__global__ __launch_bounds__(256) void k_score(
    const float* __restrict__ b0, const int* __restrict__ i0,
    const float* __restrict__ b1, const int* __restrict__ i1,
    const float* __restrict__ b2, const int* __restrict__ i2,
    const float* __restrict__ b3, const int* __restrict__ i3,
    const float* __restrict__ nullrow, const float* __restrict__ wrow,
    float* __restrict__ out, int N) {
  int g = blockIdx.x * 64 + (threadIdx.x >> 2);
  int lq = threadIdx.x & 3;
  if (g >= N) return;
  const float4* a0 = reinterpret_cast<const float4*>(b0 + i0[g] * 200);
  const float4* a1 = reinterpret_cast<const float4*>(b1 + i1[g] * 200);
  const float4* a2 = nullptr;
  const float4* a3 = nullptr;
  if constexpr (NT >= 3) {
    int ix = i2[g];
    const float* r2 = (ix >= SEQ) ? nullrow : b2 + ix * 200;
    a2 = reinterpret_cast<const float4*>(r2);
  }
  if constexpr (NT >= 4) {
    a3 = reinterpret_cast<const float4*>(b3 + i3[g] * 200);
  }
  const float4* aw = reinterpret_cast<const float4*>(wrow);
  float acc = 0.f;
#pragma unroll
  for (int j = 0; j < 13; ++j) {
    int f = j * 4 + lq;
    if (f < 50) {
      float4 s0 = a0[f];
      float4 s1 = a1[f];
      float x0 = s0.x + s1.x, x1 = s0.y + s1.y, x2 = s0.z + s1.z,
            x3 = s0.w + s1.w;
      if constexpr (NT >= 3) {
        float4 s2 = a2[f];
        x0 += s2.x; x1 += s2.y; x2 += s2.z; x3 += s2.w;
      }
      if constexpr (NT >= 4) {
        float4 s3 = a3[f];
        x0 += s3.x; x1 += s3.y; x2 += s3.z; x3 += s3.w;
      }
      float4 w = aw[f];
      acc += ftanh(x0) * w.x + ftanh(x1) * w.y + ftanh(x2) * w.z +
             ftanh(x3) * w.w;
    }
  }
  acc += __shfl_xor(acc, 1);
  acc += __shfl_xor(acc, 2);
  if (lq == 0) out[g] = acc;
}

// ---------------------------------------------------------------------------
extern "C" void kernel_launch(void* const* d_in, const int* in_sizes, int n_in,
                              void* d_out, int out_size, void* d_ws,
                              size_t ws_size, hipStream_t stream) {
  const int* words = (const int*)d_in[0];
  const int* tags = (const int*)d_in[1];
  const int* arc_head = (const int*)d_in[2];
  const int* arc_mod = (const int*)d_in[3];
  const int* sib_head = (const int*)d_in[4];
  const int* sib_mod = (const int*)d_in[5];
  const int* sib_sib = (const int*)d_in[6];
  const int* gp_head = (const int*)d_in[7];
  const int* gp_mod = (const int*)d_in[8];
  const int* gp_grand = (const int*)d_in[9];
  const int* gsib_head = (const int*)d_in[10];
  const int* gsib_mod = (const int*)d_in[11];
  const int* gsib_sib = (const int*)d_in[12];
  const int* gsib_grand = (const int*)d_in[13];
  const float* word_emb = (const float*)d_in[14];
  const float* tag_emb = (const float*)d_in[15];
  const float* Wih_f = (const float*)d_in[16];
  const float* Whh_f = (const float*)d_in[17];
  const float* b_f = (const float*)d_in[18];
  const float* Wih_b = (const float*)d_in[19];
  const float* Whh_b = (const float*)d_in[20];
  const float* b_b = (const float*)d_in[21];
  const float* W_proj = (const float*)d_in[22];
  const float* W_score = (const float*)d_in[23];
  const float* null_sib = (const float*)d_in[24];
  float* out = (float*)d_out;

  float* ws = (float*)d_ws;
  float* z_in = ws;                  // 2*256*1600 = 819200
  float* states = ws + 819200;       // 256*800   = 204800
  float* proj = ws + 1024000;        // 12*256*200 = 614400
  float* h_hist = ws + 1638400;      // 2*256*400 = 204800*? -> 819200/4... [2][256][400]=204800? no: 2*256*400=204800 floats

  // poison h_hist each launch: every word must start as SENT
  hipMemsetAsync(h_hist, 0x7F, (size_t)2 * SEQ * 400 * sizeof(float), stream);

  k_zin<<<64, 256, 0, stream>>>(words, tags, word_emb, tag_emb, Wih_f, b_f,
                                Wih_b, b_b, z_in);
  k_lstm<<<2 * NWG, 256, 0, stream>>>(Whh_f, Whh_b, z_in, states, h_hist);
  k_proj<<<12 * 16, 256, 0, stream>>>(W_proj, states, proj);

  const float* P = proj;
  const size_t TB = (size_t)SEQ * 200;
  k_score<2><<<(N_ARC + 63) / 64, 256, 0, stream>>>(
      P + 0 * TB, arc_head, P + 1 * TB, arc_mod, nullptr, nullptr, nullptr,
      nullptr, null_sib, W_score + 0, out, N_ARC);
  k_score<3><<<(N_SIB + 63) / 64, 256, 0, stream>>>(
      P + 5 * TB, sib_head, P + 6 * TB, sib_mod, P + 7 * TB, sib_sib, nullptr,
      nullptr, null_sib, W_score + 200, out + N_ARC, N_SIB);
  k_score<3><<<(N_GP + 63) / 64, 256, 0, stream>>>(
      P + 3 * TB, gp_head, P + 4 * TB, gp_mod, P + 2 * TB, gp_grand, nullptr,
      nullptr, null_sib, W_score + 400, out + N_ARC + N_SIB, N_GP);
  k_score<4><<<(N_GSIB + 63) / 64, 256, 0, stream>>>(
      P + 8 * TB, gsib_head, P + 9 * TB, gsib_mod, P + 10 * TB, gsib_sib,
      P + 11 * TB, gsib_grand, null_sib, W_score + 600,
      out + N_ARC + N_SIB + N_GP, N_GSIB);
}

// Round 3
// 731.174 us; speedup vs baseline: 1.5893x; 1.0570x over previous
//
#include <hip/hip_runtime.h>
#include <string.h>

#define SEQ 256
#define HID 400
#define NWG 25          // workgroups per LSTM direction
#define HSL 16          // h outputs per workgroup (25*16 = 400)

#define N_ARC 65536
#define N_SIB 200000
#define N_GP  200000
#define N_GSIB 300000

#define SENT64 0x7F7F7F7F7F7F7F7FULL  // memset(0x7F); |h|<=1 never matches

__device__ __forceinline__ float fsig(float x) {
  return __builtin_amdgcn_rcpf(1.f + __expf(-x));
}
__device__ __forceinline__ float ftanh(float x) {
  return 1.f - 2.f * __builtin_amdgcn_rcpf(1.f + __expf(2.f * x));
}

// ---------------------------------------------------------------------------
// Kernel 1: z_in[d][s][r] = b[r] + sum_k x_scan[d][s][k] * Wih[r][k]
// ---------------------------------------------------------------------------
__global__ __launch_bounds__(256) void k_zin(
    const int* __restrict__ words, const int* __restrict__ tags,
    const float* __restrict__ word_emb, const float* __restrict__ tag_emb,
    const float* __restrict__ Wih_f, const float* __restrict__ b_f,
    const float* __restrict__ Wih_b, const float* __restrict__ b_b,
    float* __restrict__ z_in) {
  int d = blockIdx.x >> 5;
  int st = blockIdx.x & 31;
  const float* Wih = d ? Wih_b : Wih_f;
  const float* b = d ? b_b : b_f;
  __shared__ float xs[8][120];
  int tid = threadIdx.x;
  for (int idx = tid; idx < 8 * 120; idx += 256) {
    int r = idx / 120, k = idx - r * 120;
    int s = st * 8 + r;
    int t = d ? (SEQ - 1 - s) : s;
    float v = (k < 100) ? word_emb[words[t] * 100 + k]
                        : tag_emb[tags[t] * 20 + (k - 100)];
    xs[r][k] = v;
  }
  __syncthreads();
  for (int row = tid; row < 1600; row += 256) {
    const float4* w4 = reinterpret_cast<const float4*>(Wih + row * 120);
    float bb = b[row];
    float acc[8];
#pragma unroll
    for (int r = 0; r < 8; ++r) acc[r] = bb;
    for (int k4 = 0; k4 < 30; ++k4) {
      float4 w = w4[k4];
#pragma unroll
      for (int r = 0; r < 8; ++r) {
        const float* x = &xs[r][k4 * 4];
        acc[r] += w.x * x[0] + w.y * x[1] + w.z * x[2] + w.w * x[3];
      }
    }
    for (int r = 0; r < 8; ++r) {
      int s = st * 8 + r;
      z_in[(d * SEQ + s) * 1600 + row] = acc[r];
    }
  }
}

// ---------------------------------------------------------------------------
// Kernel 2: BiLSTM recurrence, sentinel-poll broadcast.
// Weights pinned in VGPRs via opaque asm redefinition (compiler cannot
// rematerialize the loads). h exchange: producer packs pairs, 8x 8B relaxed
// agent atomic stores (one cache line/WG); consumers poll 200x u64 in
// parallel (single MALL round trip each), ds_write_b64 into LDS.
// ---------------------------------------------------------------------------
__global__ __launch_bounds__(256, 1) void k_lstm(
    const float* __restrict__ Whh_f, const float* __restrict__ Whh_b,
    const float* __restrict__ z_in,  // [2][256][1600]
    float* __restrict__ states,      // [256][800]
    float* h_hist) {                 // [2][256][400], poisoned 0x7F
  int w = blockIdx.x;
  int dir = w / NWG;
  int slot = w - dir * NWG;
  int t = threadIdx.x;
  int lr = t >> 2, q = t & 3;
  int gate = lr >> 4, jj = lr & 15;
  int row = gate * 400 + slot * HSL + jj;
  const float* Whh = dir ? Whh_b : Whh_f;

  float4 wreg[25];  // 100 VGPRs, pinned below
  const float4* wsrc =
      reinterpret_cast<const float4*>(Whh + row * 400 + q * 100);
#pragma unroll
  for (int i = 0; i < 25; ++i) wreg[i] = wsrc[i];
#pragma unroll
  for (int i = 0; i < 25; ++i) {
    asm volatile("" : "+v"(wreg[i].x), "+v"(wreg[i].y), "+v"(wreg[i].z),
                      "+v"(wreg[i].w));
  }

  __shared__ float4 h4[100];  // h[400]
  __shared__ float sums[64];
  float* h_lds = reinterpret_cast<float*>(h4);
  if (t < 100) h4[t] = make_float4(0.f, 0.f, 0.f, 0.f);
  float c = 0.f;  // valid for t<16
  const float* zbase = z_in + (size_t)dir * SEQ * 1600;
  float* hh = h_hist + (size_t)dir * SEQ * 400;
  float zv = (q == 0) ? zbase[row] : 0.f;
  __syncthreads();

  for (int s = 0;; ++s) {
    float znext = 0.f;
    if (q == 0 && s + 1 < SEQ) znext = zbase[(s + 1) * 1600 + row];
    float a0 = 0.f, a1 = 0.f, a2 = 0.f, a3 = 0.f;
    const float4* hp = h4 + q * 25;
#pragma unroll
    for (int i = 0; i < 25; ++i) {
      float4 h = hp[i];
      float4 ww = wreg[i];
      a0 += ww.x * h.x;
      a1 += ww.y * h.y;
      a2 += ww.z * h.z;
      a3 += ww.w * h.w;
    }
    float acc = (a0 + a1) + (a2 + a3);
    acc += __shfl_xor(acc, 1);
    acc += __shfl_xor(acc, 2);
    if (q == 0) sums[lr] = acc + zv;
    __syncthreads();
    if (t < HSL) {
      float zi = sums[t], zf = sums[16 + t], zg = sums[32 + t],
            zo = sums[48 + t];
      float ig = fsig(zi), fg = fsig(zf), gg = ftanh(zg), og = fsig(zo);
      c = fg * c + ig * gg;
      float hnew = og * ftanh(c);
      float h1 = __shfl(hnew, t + 1);  // pair partner (t even)
      if ((t & 1) == 0) {
        float2 f2 = make_float2(hnew, h1);
        unsigned long long u;
        memcpy(&u, &f2, 8);
        __hip_atomic_store(
            reinterpret_cast<unsigned long long*>(&hh[s * 400 + slot * HSL]) +
                (t >> 1),
            u, __ATOMIC_RELAXED, __HIP_MEMORY_SCOPE_AGENT);
      }
      int torig = dir ? (SEQ - 1 - s) : s;
      states[torig * 800 + dir * 400 + slot * HSL + t] = hnew;
    }
    if (s == SEQ - 1) break;
    // poll this step's h: 200 threads x one 8B word each, fully parallel
    if (t < 200) {
      const unsigned long long* p =
          reinterpret_cast<const unsigned long long*>(hh + s * 400) + t;
      unsigned long long u;
      do {
        u = __hip_atomic_load(p, __ATOMIC_RELAXED, __HIP_MEMORY_SCOPE_AGENT);
      } while (u == SENT64);
      reinterpret_cast<unsigned long long*>(h_lds)[t] = u;
    }
    __syncthreads();
    zv = znext;
  }
}

// ---------------------------------------------------------------------------
// Kernel 3: proj[p][s][m] = sum_k W_proj[p][m][k] * states[s][k]
// ---------------------------------------------------------------------------
__global__ __launch_bounds__(256) void k_proj(
    const float* __restrict__ W_proj,  // [12][200][800]
    const float* __restrict__ states,  // [256][800]
    float* __restrict__ proj) {        // [12][256][200]
  int p = blockIdx.x >> 4;
  int st = blockIdx.x & 15;
  __shared__ float s_lds[16][800];
  int tid = threadIdx.x;
  for (int idx = tid; idx < 16 * 800; idx += 256) {
    int si = idx / 800, k = idx - si * 800;
    s_lds[si][k] = states[(st * 16 + si) * 800 + k];
  }
  __syncthreads();
  if (tid < 200) {
    int m = tid;
    const float4* w4 =
        reinterpret_cast<const float4*>(W_proj + (p * 200 + m) * 800);
    float acc[16];
#pragma unroll
    for (int si = 0; si < 16; ++si) acc[si] = 0.f;
    for (int k4 = 0; k4 < 200; ++k4) {
      float4 w = w4[k4];
#pragma unroll
      for (int si = 0; si < 16; ++si) {
        float4 sv = *reinterpret_cast<const float4*>(&s_lds[si][k4 * 4]);
        acc[si] += w.x * sv.x + w.y * sv.y + w.z * sv.z + w.w * sv.w;
      }
    }
    for (int si = 0; si < 16; ++si)
      proj[(p * SEQ + st * 16 + si) * 200 + m] = acc[si];
  }
}

// ---------------------------------------------------------------------------
// Kernel 4: scoring, 4 lanes per output; 64B-coalesced gathered rows.
// ---------------------------------------------------------------------------
template <int NT>
__global__ __launch_bounds__(256) void k_score(
    const float* __restrict__ b0, const int* __restrict__ i0,
    const float* __restrict__ b1, const int* __restrict__ i1,
    const float* __restrict__ b2, const int* __restrict__ i2,
    const float* __restrict__ b3, const int* __restrict__ i3,
    const float* __restrict__ nullrow, const float* __restrict__ wrow,
    float* __restrict__ out, int N) {
  int g = blockIdx.x * 64 + (threadIdx.x >> 2);
  int lq = threadIdx.x & 3;
  if (g >= N) return;
  const float4* a0 = reinterpret_cast<const float4*>(b0 + i0[g] * 200);
  const float4* a1 = reinterpret_cast<const float4*>(b1 + i1[g] * 200);
  const float4* a2 = nullptr;
  const float4* a3 = nullptr;
  if constexpr (NT >= 3) {
    int ix = i2[g];
    const float* r2 = (ix >= SEQ) ? nullrow : b2 + ix * 200;
    a2 = reinterpret_cast<const float4*>(r2);
  }
  if constexpr (NT >= 4) {
    a3 = reinterpret_cast<const float4*>(b3 + i3[g] * 200);
  }
  const float4* aw = reinterpret_cast<const float4*>(wrow);
  float acc = 0.f;
#pragma unroll
  for (int j = 0; j < 13; ++j) {
    int f = j * 4 + lq;
    if (f < 50) {
      float4 s0 = a0[f];
      float4 s1 = a1[f];
      float x0 = s0.x + s1.x, x1 = s0.y + s1.y, x2 = s0.z + s1.z,
            x3 = s0.w + s1.w;
      if constexpr (NT >= 3) {
        float4 s2 = a2[f];
        x0 += s2.x; x1 += s2.y; x2 += s2.z; x3 += s2.w;
      }
      if constexpr (NT >= 4) {
        float4 s3 = a3[f];
        x0 += s3.x; x1 += s3.y; x2 += s3.z; x3 += s3.w;
      }
      float4 w = aw[f];
      acc += ftanh(x0) * w.x + ftanh(x1) * w.y + ftanh(x2) * w.z +
             ftanh(x3) * w.w;
    }
  }
  acc += __shfl_xor(acc, 1);
  acc += __shfl_xor(acc, 2);
  if (lq == 0) out[g] = acc;
}

// ---------------------------------------------------------------------------
extern "C" void kernel_launch(void* const* d_in, const int* in_sizes, int n_in,
                              void* d_out, int out_size, void* d_ws,
                              size_t ws_size, hipStream_t stream) {
  const int* words = (const int*)d_in[0];
  const int* tags = (const int*)d_in[1];
  const int* arc_head = (const int*)d_in[2];
  const int* arc_mod = (const int*)d_in[3];
  const int* sib_head = (const int*)d_in[4];
  const int* sib_mod = (const int*)d_in[5];
  const int* sib_sib = (const int*)d_in[6];
  const int* gp_head = (const int*)d_in[7];
  const int* gp_mod = (const int*)d_in[8];
  const int* gp_grand = (const int*)d_in[9];
  const int* gsib_head = (const int*)d_in[10];
  const int* gsib_mod = (const int*)d_in[11];
  const int* gsib_sib = (const int*)d_in[12];
  const int* gsib_grand = (const int*)d_in[13];
  const float* word_emb = (const float*)d_in[14];
  const float* tag_emb = (const float*)d_in[15];
  const float* Wih_f = (const float*)d_in[16];
  const float* Whh_f = (const float*)d_in[17];
  const float* b_f = (const float*)d_in[18];
  const float* Wih_b = (const float*)d_in[19];
  const float* Whh_b = (const float*)d_in[20];
  const float* b_b = (const float*)d_in[21];
  const float* W_proj = (const float*)d_in[22];
  const float* W_score = (const float*)d_in[23];
  const float* null_sib = (const float*)d_in[24];
  float* out = (float*)d_out;

  float* ws = (float*)d_ws;
  float* z_in = ws;              // 2*256*1600 = 819200 floats
  float* states = ws + 819200;   // 256*800    = 204800
  float* proj = ws + 1024000;    // 12*256*200 = 614400
  float* h_hist = ws + 1638400;  // 2*256*400  = 204800

  // every 8B word of h_hist must start as sentinel each launch
  hipMemsetAsync(h_hist, 0x7F, (size_t)2 * SEQ * 400 * sizeof(float), stream);

  k_zin<<<64, 256, 0, stream>>>(words, tags, word_emb, tag_emb, Wih_f, b_f,
                                Wih_b, b_b, z_in);
  k_lstm<<<2 * NWG, 256, 0, stream>>>(Whh_f, Whh_b, z_in, states, h_hist);
  k_proj<<<12 * 16, 256, 0, stream>>>(W_proj, states, proj);

  const float* P = proj;
  const size_t TB = (size_t)SEQ * 200;
  k_score<2><<<(N_ARC + 63) / 64, 256, 0, stream>>>(
      P + 0 * TB, arc_head, P + 1 * TB, arc_mod, nullptr, nullptr, nullptr,
      nullptr, null_sib, W_score + 0, out, N_ARC);
  k_score<3><<<(N_SIB + 63) / 64, 256, 0, stream>>>(
      P + 5 * TB, sib_head, P + 6 * TB, sib_mod, P + 7 * TB, sib_sib, nullptr,
      nullptr, null_sib, W_score + 200, out + N_ARC, N_SIB);
  k_score<3><<<(N_GP + 63) / 64, 256, 0, stream>>>(
      P + 3 * TB, gp_head, P + 4 * TB, gp_mod, P + 2 * TB, gp_grand, nullptr,
      nullptr, null_sib, W_score + 400, out + N_ARC + N_SIB, N_GP);
  k_score<4><<<(N_GSIB + 63) / 64, 256, 0, stream>>>(
      P + 8 * TB, gsib_head, P + 9 * TB, gsib_mod, P + 10 * TB, gsib_sib,
      P + 11 * TB, gsib_grand, null_sib, W_score + 600,
      out + N_ARC + N_SIB + N_GP, N_GSIB);
}